// Round 2
// baseline (661.687 us; speedup 1.0000x reference)
//
#include <hip/hip_runtime.h>
#include <hip/hip_bf16.h>

// Causal linear attention, chunkwise, bf16 MFMA. Shapes fixed by reference:
// [N=4, L=4096, H=16, D=64], M=64, CHUNK=128, G=32.
static constexpr int Nn = 4, Ll = 4096, Hh = 16, Dd = 64, Mm = 64, Cc = 128, Gg = 32;
static constexpr int SR = 65;            // chunk-state rows: 64 kv^T rows + 1 ksum row
static constexpr int SELEMS = SR * 64;   // 4160 fp32 per (n,g,h) chunk state

typedef short bf16x8 __attribute__((ext_vector_type(8)));
typedef float f32x4 __attribute__((ext_vector_type(4)));
#define MFMA16(a, b, c) __builtin_amdgcn_mfma_f32_16x16x32_bf16(a, b, c, 0, 0, 0)

__device__ __forceinline__ float phi(float x) { return x > 0.f ? x + 1.f : __expf(x); }
__device__ __forceinline__ unsigned short f2b(float f) {
    union { float f; unsigned u; } c; c.f = f;
    return (unsigned short)((c.u + 0x7FFFu + ((c.u >> 16) & 1u)) >> 16);  // RNE
}

// ---------------------------------------------------------------------------
// Kernel 1: per-chunk kv^T[m][d] = sum_c v[c][m] phi(k)[c][d], row 64 = ksum[d].
// One wave per chunk, no LDS: A/B fragments gathered directly from global
// (quad-wise 64B segments, every line fully consumed). Ones-row A-frag (m=64)
// produces the ksum row in the same MFMAs.
// ---------------------------------------------------------------------------
__global__ __launch_bounds__(64) void kv_state_kernel(
    const float* __restrict__ keys, const float* __restrict__ values,
    float* __restrict__ kvws)
{
    const int b = blockIdx.x;                 // chunk id = (n*32+g)*16+h
    const int lane = threadIdx.x, quad = lane >> 4, l16 = lane & 15;
    const int h = b & 15, g = (b >> 4) & 31, n = b >> 9;
    const size_t base = ((size_t)(n * Ll + g * Cc) * Hh + h) * Dd;

    f32x4 acc[5][4];
    #pragma unroll
    for (int mt = 0; mt < 5; ++mt)
        #pragma unroll
        for (int dt = 0; dt < 4; ++dt) acc[mt][dt] = f32x4{0.f, 0.f, 0.f, 0.f};

    bf16x8 a4;  // ones row (m=64) lives in lanes l16==0; other rows discarded
    #pragma unroll
    for (int j = 0; j < 8; ++j) a4[j] = (l16 == 0) ? (short)0x3F80 : (short)0;

    for (int k0 = 0; k0 < 4; ++k0) {
        const int cb = k0 * 32 + quad * 8;
        bf16x8 bfr[4];  // B[k=c][j=d] = phi(k)[c][d]
        #pragma unroll
        for (int dt = 0; dt < 4; ++dt) {
            const float* p = keys + base + (size_t)cb * 1024 + dt * 16 + l16;
            #pragma unroll
            for (int j = 0; j < 8; ++j) bfr[dt][j] = (short)f2b(phi(p[(size_t)j * 1024]));
        }
        bf16x8 afr[5];  // A[m][c] = v[c][m]
        #pragma unroll
        for (int mt = 0; mt < 4; ++mt) {
            const float* p = values + base + (size_t)cb * 1024 + mt * 16 + l16;
            #pragma unroll
            for (int j = 0; j < 8; ++j) afr[mt][j] = (short)f2b(p[(size_t)j * 1024]);
        }
        afr[4] = a4;
        #pragma unroll
        for (int mt = 0; mt < 5; ++mt)
            #pragma unroll
            for (int dt = 0; dt < 4; ++dt)
                acc[mt][dt] = MFMA16(afr[mt], bfr[dt], acc[mt][dt]);
    }

    float* o = kvws + (size_t)b * SELEMS;
    #pragma unroll
    for (int mt = 0; mt < 4; ++mt)
        #pragma unroll
        for (int dt = 0; dt < 4; ++dt)
            #pragma unroll
            for (int r = 0; r < 4; ++r)
                o[(mt * 16 + quad * 4 + r) * 64 + dt * 16 + l16] = acc[mt][dt][r];
    if (quad == 0) {  // ksum row (D row 64, reg 0)
        #pragma unroll
        for (int dt = 0; dt < 4; ++dt) o[64 * 64 + dt * 16 + l16] = acc[4][dt][0];
    }
}

// ---------------------------------------------------------------------------
// Kernel 2: in-place exclusive prefix over g, uniform over all 65x64 state
// elements. Coalesced over e at each g.
// ---------------------------------------------------------------------------
__global__ __launch_bounds__(256) void prefix_kernel(float* __restrict__ kvws)
{
    const int t = blockIdx.x * 256 + threadIdx.x;  // < 4*16*4160 = 266240 exact
    const int n = t / (Hh * SELEMS);
    const int rem = t - n * (Hh * SELEMS);
    const int h = rem / SELEMS;
    const int e = rem - h * SELEMS;
    float run = 0.f;
    for (int g = 0; g < Gg; ++g) {
        const size_t idx = ((size_t)((n * Gg + g) * Hh + h)) * SELEMS + e;
        const float val = kvws[idx];
        kvws[idx] = run;
        run += val;
    }
}

// ---------------------------------------------------------------------------
// Kernel 3: one block per (n,g,h); wave w owns 16-row tiles rt = w and w+4.
//   S = phi(Q) phi(K)^T (causal)  -> bf16 via per-wave sb
//   acc = S_masked . V  +  Q . KV_prev      (K-dim causally truncated)
//   z via augmentation: vtb row 64 = ones (rowsum S), kvtb row 64 = kpre.
//   B-frag rows 65..79 read garbage -> columns 65..79 only -> discarded.
// ---------------------------------------------------------------------------
__global__ __launch_bounds__(256) void out_kernel(
    const float* __restrict__ q, const float* __restrict__ k,
    const float* __restrict__ v, const float* __restrict__ kvws,
    float* __restrict__ out)
{
    // ushort LDS pool, manual layout (element offsets), 62880 B total:
    //   kb   [128][72] @ 0      phi(k) row-major (+8 pad: 16B-aligned frags, 2-way banks)
    //   kvtb [65][72]  @ 9216   kv_prev^T (+kpre row); overreads spill into vtb (harmless)
    //   vtb  [65][136] @ 13896  v^T (+ones row); overreads spill into sb (harmless)
    //   sb   [4][16][136] @ 22736  per-wave masked scores (bf16)
    __shared__ __align__(16) unsigned short lds[31440];
    unsigned short* kb   = lds;
    unsigned short* kvtb = lds + 9216;
    unsigned short* vtb  = lds + 13896;
    unsigned short* sb0  = lds + 22736;

    const int b = blockIdx.x;
    const int h = b & 15, g = (b >> 4) & 31, n = b >> 9;
    const int tid = threadIdx.x;
    const int wave = tid >> 6, lane = tid & 63, quad = lane >> 4, l16 = lane & 15;
    const size_t base = ((size_t)(n * Ll + g * Cc) * Hh + h) * Dd;
    const float* kvp = kvws + (size_t)((n * Gg + g) * Hh + h) * SELEMS;

    // ---- stage kb: phi(k), row-major, float4-coalesced ----
    for (int i = tid; i < 2048; i += 256) {
        const int c = i >> 4, dg = (i & 15) << 2;
        float4 f = *(const float4*)(k + base + (size_t)c * 1024 + dg);
        uint2 w;
        w.x = (unsigned)f2b(phi(f.x)) | ((unsigned)f2b(phi(f.y)) << 16);
        w.y = (unsigned)f2b(phi(f.z)) | ((unsigned)f2b(phi(f.w)) << 16);
        *(uint2*)&kb[c * 72 + dg] = w;
    }
    // ---- stage kvtb from fp32 state [65][64] ----
    for (int i = tid; i < SR * 16; i += 256) {
        const int m = i >> 4, dg = (i & 15) << 2;
        float4 f = *(const float4*)(kvp + m * 64 + dg);
        uint2 w;
        w.x = (unsigned)f2b(f.x) | ((unsigned)f2b(f.y) << 16);
        w.y = (unsigned)f2b(f.z) | ((unsigned)f2b(f.w) << 16);
        *(uint2*)&kvtb[m * 72 + dg] = w;
    }
    // ---- stage vtb: v^T via frag-pattern gather, one 16B LDS write each ----
    #pragma unroll
    for (int it = 0; it < 4; ++it) {
        const int id = wave * 4 + it;
        const int m0 = (id & 3) * 16, cb = (id >> 2) * 32;
        const float* p = v + base + (size_t)(cb + quad * 8) * 1024 + m0 + l16;
        bf16x8 fr;
        #pragma unroll
        for (int j = 0; j < 8; ++j) fr[j] = (short)f2b(p[(size_t)j * 1024]);
        *(bf16x8*)&vtb[(m0 + l16) * 136 + cb + quad * 8] = fr;
    }
    if (tid < 128) vtb[64 * 136 + tid] = (unsigned short)0x3F80;  // ones row
    __syncthreads();

    unsigned short* sbw = sb0 + wave * 16 * 136;

    #pragma unroll
    for (int rr = 0; rr < 2; ++rr) {
        const int rt = wave + rr * 4;
        // Q A-frags from global (16 rows x 256B, lines fully consumed)
        bf16x8 aq0, aq1;
        {
            const float* qp = q + base + (size_t)(rt * 16 + l16) * 1024 + quad * 8;
            float4 f0 = *(const float4*)(qp);
            float4 f1 = *(const float4*)(qp + 4);
            float4 f2 = *(const float4*)(qp + 32);
            float4 f3 = *(const float4*)(qp + 36);
            aq0[0] = (short)f2b(phi(f0.x)); aq0[1] = (short)f2b(phi(f0.y));
            aq0[2] = (short)f2b(phi(f0.z)); aq0[3] = (short)f2b(phi(f0.w));
            aq0[4] = (short)f2b(phi(f1.x)); aq0[5] = (short)f2b(phi(f1.y));
            aq0[6] = (short)f2b(phi(f1.z)); aq0[7] = (short)f2b(phi(f1.w));
            aq1[0] = (short)f2b(phi(f2.x)); aq1[1] = (short)f2b(phi(f2.y));
            aq1[2] = (short)f2b(phi(f2.z)); aq1[3] = (short)f2b(phi(f2.w));
            aq1[4] = (short)f2b(phi(f3.x)); aq1[5] = (short)f2b(phi(f3.y));
            aq1[6] = (short)f2b(phi(f3.z)); aq1[7] = (short)f2b(phi(f3.w));
        }
        // ---- scores S = Q K^T, causal mask, bf16 -> sb ----
        for (int ct = 0; ct <= rt; ++ct) {
            bf16x8 b0 = *(const bf16x8*)&kb[(ct * 16 + l16) * 72 + quad * 8];
            bf16x8 b1 = *(const bf16x8*)&kb[(ct * 16 + l16) * 72 + 32 + quad * 8];
            f32x4 s = f32x4{0.f, 0.f, 0.f, 0.f};
            s = MFMA16(aq0, b0, s);
            s = MFMA16(aq1, b1, s);
            if (ct == rt) {
                #pragma unroll
                for (int r = 0; r < 4; ++r)
                    sbw[(quad * 4 + r) * 136 + ct * 16 + l16] =
                        f2b(l16 <= quad * 4 + r ? s[r] : 0.f);
            } else {
                #pragma unroll
                for (int r = 0; r < 4; ++r)
                    sbw[(quad * 4 + r) * 136 + ct * 16 + l16] = f2b(s[r]);
            }
        }
        if ((rt & 1) == 0) {  // zero-pad cols to 32-boundary for the K-loop
            const int row = lane & 15, cg = (lane >> 4) * 4;
            *(uint2*)&sbw[row * 136 + (rt + 1) * 16 + cg] = uint2{0u, 0u};
        }
        // within-wave LDS RAW: compiler-inserted lgkmcnt waits, no barrier needed
        const int kk = (rt + 2) >> 1;  // 32-wide K chunks (causally truncated)
        bf16x8 as[4];
        for (int kc = 0; kc < kk; ++kc)
            as[kc] = *(const bf16x8*)&sbw[l16 * 136 + kc * 32 + quad * 8];
        f32x4 accT[5];
        #pragma unroll
        for (int mt = 0; mt < 5; ++mt) {
            f32x4 t = f32x4{0.f, 0.f, 0.f, 0.f};
            for (int kc = 0; kc < kk; ++kc) {
                bf16x8 bv = *(const bf16x8*)&vtb[(mt * 16 + l16) * 136 + kc * 32 + quad * 8];
                t = MFMA16(as[kc], bv, t);
            }
            bf16x8 g0 = *(const bf16x8*)&kvtb[(mt * 16 + l16) * 72 + quad * 8];
            bf16x8 g1 = *(const bf16x8*)&kvtb[(mt * 16 + l16) * 72 + 32 + quad * 8];
            t = MFMA16(aq0, g0, t);
            t = MFMA16(aq1, g1, t);
            accT[mt] = t;
        }
        // ---- z from col 64 (mt=4, lanes l16==0), broadcast within quad ----
        float iz[4];
        #pragma unroll
        for (int r = 0; r < 4; ++r) {
            float zv = __shfl(accT[4][r], quad << 4, 64);
            iz[r] = 1.0f / (zv + 1e-6f);
        }
        // ---- divide + store ----
        float* op = out + base + (size_t)(rt * 16) * 1024;
        #pragma unroll
        for (int mt = 0; mt < 4; ++mt)
            #pragma unroll
            for (int r = 0; r < 4; ++r)
                op[(size_t)(quad * 4 + r) * 1024 + mt * 16 + l16] = accT[mt][r] * iz[r];
    }
}

extern "C" void kernel_launch(void* const* d_in, const int* in_sizes, int n_in,
                              void* d_out, int out_size, void* d_ws, size_t ws_size,
                              hipStream_t stream) {
    const float* q = (const float*)d_in[0];
    const float* k = (const float*)d_in[1];
    const float* v = (const float*)d_in[2];
    float* out = (float*)d_out;
    float* kvws = (float*)d_ws;  // 2048 chunks x 4160 fp32 = 34.1 MB

    kv_state_kernel<<<Nn * Gg * Hh, 64, 0, stream>>>(k, v, kvws);
    prefix_kernel<<<(Nn * Hh * SELEMS) / 256, 256, 0, stream>>>(kvws);
    out_kernel<<<Nn * Gg * Hh, 256, 0, stream>>>(q, k, v, kvws, out);
}

// Round 3
// 632.232 us; speedup vs baseline: 1.0466x; 1.0466x over previous
//
#include <hip/hip_runtime.h>
#include <hip/hip_bf16.h>

// Causal linear attention, chunkwise, bf16 MFMA. Shapes fixed by reference:
// [N=4, L=4096, H=16, D=64], M=64, CHUNK=128, G=32.
static constexpr int Nn = 4, Ll = 4096, Hh = 16, Dd = 64, Mm = 64, Cc = 128, Gg = 32;
static constexpr int SR = 65;              // state rows: 64 kv^T rows + 1 ksum row
static constexpr int SELEMS = SR * 64;     // 4160 bf16 per chunk state
static constexpr int VTELEMS = SR * 128;   // 8320 bf16 per chunk v^T (row 64 = ones)

typedef short bf16x8 __attribute__((ext_vector_type(8)));
typedef float f32x4 __attribute__((ext_vector_type(4)));
#define MFMA16(a, b, c) __builtin_amdgcn_mfma_f32_16x16x32_bf16(a, b, c, 0, 0, 0)

__device__ __forceinline__ float phi(float x) { return x > 0.f ? x + 1.f : __expf(x); }
__device__ __forceinline__ unsigned short f2b(float f) {
    union { float f; unsigned u; } c; c.f = f;
    return (unsigned short)((c.u + 0x7FFFu + ((c.u >> 16) & 1u)) >> 16);  // RNE
}
__device__ __forceinline__ float b2f(unsigned short u) {
    union { unsigned u; float f; } c; c.u = (unsigned)u << 16;
    return c.f;
}

// ---------------------------------------------------------------------------
// Kernel 1: per chunk, emit bf16 v^T [65][128] (row 64 = ones) and bf16 state
// kv^T [65][64] (row 64 = ksum). One block per chunk; wave w owns m-rows
// [16w,16w+16); wave 0 additionally does the ones/ksum row.
// ---------------------------------------------------------------------------
__global__ __launch_bounds__(256) void kv_state_kernel(
    const float* __restrict__ k, const float* __restrict__ v,
    unsigned short* __restrict__ vT, unsigned short* __restrict__ stateB)
{
    __shared__ unsigned short kb[128 * 68];  // phi(k) bf16 row-major, 17408 B

    const int b = blockIdx.x;  // chunk = (n*32+g)*16+h
    const int h = b & 15, g = (b >> 4) & 31, n = b >> 9;
    const int tid = threadIdx.x;
    const int wave = tid >> 6, lane = tid & 63, quad = lane >> 4, l16 = lane & 15;
    const size_t base = ((size_t)(n * Ll + g * Cc) * Hh + h) * Dd;

    // stage phi(k) bf16, float4-coalesced reads, conflict-lite uint2 stores
    for (int i = tid; i < 2048; i += 256) {
        const int c = i >> 4, dg = (i & 15) << 2;
        float4 f = *(const float4*)(k + base + (size_t)c * 1024 + dg);
        uint2 w;
        w.x = (unsigned)f2b(phi(f.x)) | ((unsigned)f2b(phi(f.y)) << 16);
        w.y = (unsigned)f2b(phi(f.z)) | ((unsigned)f2b(phi(f.w)) << 16);
        *(uint2*)&kb[c * 68 + dg] = w;
    }

    unsigned short* vTo = vT + (size_t)b * VTELEMS;
    unsigned short* stO = stateB + (size_t)b * SELEMS;
    if (tid < 32) {  // ones row of v^T (row 64)
        uint2 w; w.x = 0x3F803F80u; w.y = 0x3F803F80u;
        *(uint2*)&vTo[64 * 128 + tid * 4] = w;
    }
    __syncthreads();

    bf16x8 aones;
    #pragma unroll
    for (int j = 0; j < 8; ++j) aones[j] = (l16 == 0) ? (short)0x3F80 : (short)0;

    f32x4 acc[4], acc4[4];
    #pragma unroll
    for (int dt = 0; dt < 4; ++dt) { acc[dt] = f32x4{0,0,0,0}; acc4[dt] = f32x4{0,0,0,0}; }

    for (int k0 = 0; k0 < 4; ++k0) {
        // A-frag: v^T row m=16*wave+l16, cols c = 32*k0+quad*8+j (global gather)
        const float* p = v + base + (size_t)(32 * k0 + quad * 8) * 1024 + 16 * wave + l16;
        bf16x8 af;
        #pragma unroll
        for (int j = 0; j < 8; ++j) af[j] = (short)f2b(p[(size_t)j * 1024]);
        *(bf16x8*)&vTo[(16 * wave + l16) * 128 + 32 * k0 + quad * 8] = af;
        #pragma unroll
        for (int dt = 0; dt < 4; ++dt) {
            bf16x8 bf;
            #pragma unroll
            for (int j = 0; j < 8; ++j)
                bf[j] = (short)kb[(32 * k0 + quad * 8 + j) * 68 + 16 * dt + l16];
            acc[dt] = MFMA16(af, bf, acc[dt]);
            if (wave == 0) acc4[dt] = MFMA16(aones, bf, acc4[dt]);
        }
    }
    #pragma unroll
    for (int dt = 0; dt < 4; ++dt)
        #pragma unroll
        for (int r = 0; r < 4; ++r)
            stO[(16 * wave + quad * 4 + r) * 64 + 16 * dt + l16] = f2b(acc[dt][r]);
    if (wave == 0 && quad == 0) {
        #pragma unroll
        for (int dt = 0; dt < 4; ++dt) stO[64 * 64 + 16 * dt + l16] = f2b(acc4[dt][0]);
    }
}

// ---------------------------------------------------------------------------
// Kernel 2: in-place exclusive prefix over g on the bf16 state (fp32 accum).
// Each (n,h,e) series owned by exactly one thread -> in-place is safe.
// ---------------------------------------------------------------------------
__global__ __launch_bounds__(256) void prefix_kernel(unsigned short* __restrict__ st)
{
    const int t = blockIdx.x * 256 + threadIdx.x;  // 1040*256 = 266240 exact
    const int n = t / (Hh * SELEMS);
    const int rem = t - n * (Hh * SELEMS);
    const int h = rem / SELEMS;
    const int e = rem - h * SELEMS;
    float run = 0.f;
    for (int g = 0; g < Gg; ++g) {
        const size_t idx = ((size_t)((n * Gg + g) * Hh + h)) * SELEMS + e;
        const float val = b2f(st[idx]);
        st[idx] = f2b(run);
        run += val;
    }
}

// ---------------------------------------------------------------------------
// Kernel 3: one block per chunk; wave w owns rt in {w, 7-w} (balanced).
// LDS: phi(k) (18 KB) + per-wave score buffers (17 KB) = 35.8 KB -> 4 blk/CU.
// v^T and state B-frags are 16B global loads (L2/L3-resident, zero VALU).
// z via augmentation: v^T row 64 = ones, state row 64 = prefixed ksum.
// ---------------------------------------------------------------------------
__global__ __launch_bounds__(256) void out_kernel(
    const float* __restrict__ q, const float* __restrict__ k,
    const unsigned short* __restrict__ vT, const unsigned short* __restrict__ stateB,
    float* __restrict__ out)
{
    __shared__ unsigned short kb[128 * 72];      // 18432 B, phi(k) row-major
    __shared__ unsigned short sb[4][16 * 136];   // 17408 B, per-wave masked scores

    const int b = blockIdx.x;
    const int h = b & 15, g = (b >> 4) & 31, n = b >> 9;
    const int tid = threadIdx.x;
    const int wave = tid >> 6, lane = tid & 63, quad = lane >> 4, l16 = lane & 15;
    const size_t base = ((size_t)(n * Ll + g * Cc) * Hh + h) * Dd;
    const unsigned short* vTc = vT + (size_t)b * VTELEMS;
    const unsigned short* stc = stateB + (size_t)b * SELEMS;

    for (int i = tid; i < 2048; i += 256) {
        const int c = i >> 4, dg = (i & 15) << 2;
        float4 f = *(const float4*)(k + base + (size_t)c * 1024 + dg);
        uint2 w;
        w.x = (unsigned)f2b(phi(f.x)) | ((unsigned)f2b(phi(f.y)) << 16);
        w.y = (unsigned)f2b(phi(f.z)) | ((unsigned)f2b(phi(f.w)) << 16);
        *(uint2*)&kb[c * 72 + dg] = w;
    }
    __syncthreads();

    unsigned short* sbw = sb[wave];

    #pragma unroll
    for (int rr = 0; rr < 2; ++rr) {
        const int rt = (rr == 0) ? wave : 7 - wave;
        // Q A-frags straight from global fp32 (rows rt*16+l16)
        bf16x8 aq0, aq1;
        {
            const float* qp = q + base + (size_t)(rt * 16 + l16) * 1024 + quad * 8;
            float4 f0 = *(const float4*)(qp);
            float4 f1 = *(const float4*)(qp + 4);
            float4 f2 = *(const float4*)(qp + 32);
            float4 f3 = *(const float4*)(qp + 36);
            aq0[0] = (short)f2b(phi(f0.x)); aq0[1] = (short)f2b(phi(f0.y));
            aq0[2] = (short)f2b(phi(f0.z)); aq0[3] = (short)f2b(phi(f0.w));
            aq0[4] = (short)f2b(phi(f1.x)); aq0[5] = (short)f2b(phi(f1.y));
            aq0[6] = (short)f2b(phi(f1.z)); aq0[7] = (short)f2b(phi(f1.w));
            aq1[0] = (short)f2b(phi(f2.x)); aq1[1] = (short)f2b(phi(f2.y));
            aq1[2] = (short)f2b(phi(f2.z)); aq1[3] = (short)f2b(phi(f2.w));
            aq1[4] = (short)f2b(phi(f3.x)); aq1[5] = (short)f2b(phi(f3.y));
            aq1[6] = (short)f2b(phi(f3.z)); aq1[7] = (short)f2b(phi(f3.w));
        }
        // scores S = Q K^T, causal mask, bf16 -> sbw
        for (int ct = 0; ct <= rt; ++ct) {
            bf16x8 b0 = *(const bf16x8*)&kb[(ct * 16 + l16) * 72 + quad * 8];
            bf16x8 b1 = *(const bf16x8*)&kb[(ct * 16 + l16) * 72 + 32 + quad * 8];
            f32x4 s = f32x4{0.f, 0.f, 0.f, 0.f};
            s = MFMA16(aq0, b0, s);
            s = MFMA16(aq1, b1, s);
            if (ct == rt) {
                #pragma unroll
                for (int r = 0; r < 4; ++r)
                    sbw[(quad * 4 + r) * 136 + ct * 16 + l16] =
                        f2b(l16 <= quad * 4 + r ? s[r] : 0.f);
            } else {
                #pragma unroll
                for (int r = 0; r < 4; ++r)
                    sbw[(quad * 4 + r) * 136 + ct * 16 + l16] = f2b(s[r]);
            }
        }
        if ((rt & 1) == 0) {  // zero-pad score cols to the 32 boundary
            const int row = lane & 15, cg = (lane >> 4) * 4;
            *(uint2*)&sbw[row * 136 + (rt + 1) * 16 + cg] = uint2{0u, 0u};
        }
        // within-wave LDS RAW: compiler lgkmcnt ordering suffices (no barrier)
        const int kk = (rt + 2) >> 1;
        bf16x8 as[4];
        for (int kc = 0; kc < kk; ++kc)
            as[kc] = *(const bf16x8*)&sbw[l16 * 136 + kc * 32 + quad * 8];
        f32x4 accT[5];
        #pragma unroll
        for (int mt = 0; mt < 5; ++mt) {
            f32x4 t = f32x4{0.f, 0.f, 0.f, 0.f};
            for (int kc = 0; kc < kk; ++kc) {
                bf16x8 bv = *(const bf16x8*)&vTc[(mt * 16 + l16) * 128 + kc * 32 + quad * 8];
                t = MFMA16(as[kc], bv, t);
            }
            bf16x8 g0 = *(const bf16x8*)&stc[(mt * 16 + l16) * 64 + quad * 8];
            bf16x8 g1 = *(const bf16x8*)&stc[(mt * 16 + l16) * 64 + 32 + quad * 8];
            t = MFMA16(aq0, g0, t);
            t = MFMA16(aq1, g1, t);
            accT[mt] = t;
        }
        float iz[4];
        #pragma unroll
        for (int r = 0; r < 4; ++r) {
            float zv = __shfl(accT[4][r], quad << 4, 64);
            iz[r] = 1.0f / (zv + 1e-6f);
        }
        float* op = out + base + (size_t)(rt * 16) * 1024;
        #pragma unroll
        for (int mt = 0; mt < 4; ++mt)
            #pragma unroll
            for (int r = 0; r < 4; ++r)
                op[(size_t)(quad * 4 + r) * 1024 + mt * 16 + l16] = accT[mt][r] * iz[r];
    }
}

extern "C" void kernel_launch(void* const* d_in, const int* in_sizes, int n_in,
                              void* d_out, int out_size, void* d_ws, size_t ws_size,
                              hipStream_t stream) {
    const float* q = (const float*)d_in[0];
    const float* k = (const float*)d_in[1];
    const float* v = (const float*)d_in[2];
    float* out = (float*)d_out;

    // ws: v^T bf16 (2048 x 8320 + pad) then state bf16 (2048 x 4160 + pad) ~51 MB
    unsigned short* vT = (unsigned short*)d_ws;
    unsigned short* stateB = vT + (size_t)2048 * VTELEMS + 2048;

    kv_state_kernel<<<Nn * Gg * Hh, 256, 0, stream>>>(k, v, vT, stateB);
    prefix_kernel<<<(Nn * Hh * SELEMS) / 256, 256, 0, stream>>>(stateB);
    out_kernel<<<Nn * Gg * Hh, 256, 0, stream>>>(q, k, vT, stateB, out);
}